// Round 3
// baseline (593.092 us; speedup 1.0000x reference)
//
#include <hip/hip_runtime.h>
#include <math.h>

// Problem constants (B, N, L, D) from the reference setup_inputs().
#define BSZ 64
#define NN  128
#define LL  64
#define DD  768
#define NEGV (-9e9f)

#define TQ (BSZ * NN * DD / 4)   // text float4 count  = 1572864
#define IQ (BSZ * LL * DD / 4)   // image float4 count =  786432

typedef _Float16 f16x8 __attribute__((ext_vector_type(8)));  // 8 f16 = 4 VGPRs
typedef __attribute__((ext_vector_type(4))) float f32x4;     // MFMA 16x16 accum

// async 16B global -> LDS (dest = wave-uniform base + lane*16)
__device__ __forceinline__ void gl_lds16(const void* g, void* l) {
    __builtin_amdgcn_global_load_lds(
        (const __attribute__((address_space(1))) void*)g,
        (__attribute__((address_space(3))) void*)l, 16, 0, 0);
}

// ---------------------------------------------------------------------------
// Kernel 0: fp32 -> fp16 (RTN).
// ---------------------------------------------------------------------------
__global__ __launch_bounds__(256) void k_prep(
    const float4* __restrict__ t4, const float4* __restrict__ g4,
    ushort4* __restrict__ A, ushort4* __restrict__ B)
{
    int id = blockIdx.x * 256 + threadIdx.x;
    const float4* src; ushort4* dst; int idx;
    if (id < TQ) { src = t4; dst = A; idx = id; }
    else         { src = g4; dst = B; idx = id - TQ; }
    float4 x = src[idx];
    _Float16 h0 = (_Float16)x.x, h1 = (_Float16)x.y;
    _Float16 h2 = (_Float16)x.z, h3 = (_Float16)x.w;
    ushort4 o;
    o.x = __builtin_bit_cast(unsigned short, h0);
    o.y = __builtin_bit_cast(unsigned short, h1);
    o.z = __builtin_bit_cast(unsigned short, h2);
    o.w = __builtin_bit_cast(unsigned short, h3);
    dst[idx] = o;
}

// ---------------------------------------------------------------------------
// Stage one BK=32 chunk into LDS, k8-major layout (conflict-free reads):
//   A region  8 KB: slot = k8*128 + r   (k8 in [0,4), r in [0,128))
//   B region 16 KB: slot = k8*256 + c   (c in [0,256) = 4 image rows)
// global_load_lds dest = wave-uniform base + lane*16; global src is per-lane,
// so src = row*DD + k0 + k8*8 realizes the k8-major layout with linear dest.
// 512 threads x 3 calls = 1536 x 16B slots = 24 KB.
// ---------------------------------------------------------------------------
__device__ __forceinline__ void stage_chunk(
    const unsigned short* __restrict__ pa, const unsigned short* __restrict__ pb,
    int k0, char* buf, int wave, int lane)
{
    int s = wave * 64 + lane;          // 0..511
    // A: slots 0..511
    {
        int k8 = s >> 7, r = s & 127;
        gl_lds16(pa + (size_t)r * DD + k0 + k8 * 8, buf + wave * 1024);
    }
    // B: slots 0..511
    {
        int k8 = s >> 8, c = s & 255;
        gl_lds16(pb + (size_t)c * DD + k0 + k8 * 8, buf + 8192 + wave * 1024);
    }
    // B: slots 512..1023
    {
        int s2 = s + 512;
        int k8 = s2 >> 8, c = s2 & 255;
        gl_lds16(pb + (size_t)c * DD + k0 + k8 * 8, buf + 16384 + wave * 1024);
    }
}

// ---------------------------------------------------------------------------
// Kernel 1: one block per (i, jj4) where jj4 covers j = {4jj4..4jj4+3}.
// C[128][256] = text[i] @ [image[j0..j0+3]]^T, fp16 MFMA, BK=32 chunks,
// double-buffered global_load_lds staging, 512 threads = 8 waves (2 row x
// 4 col groups, 64x64 per wave -> acc[4][4]).
// LDS 52.5 KB -> 3 blocks/CU (24 waves) vs prior 73.7 KB / 2 blocks.
// Epilogue: stage buffers are dead -> reuse as Cs[128][65] (one 64-col jh
// half at a time, 4 passes); masked row/col softmax reductions; S + diag W.
// ---------------------------------------------------------------------------
__global__ __launch_bounds__(512, 6) void k_scores(
    const unsigned short* __restrict__ A, const unsigned short* __restrict__ B,
    const int* __restrict__ tmask, const int* __restrict__ imask,
    float* __restrict__ S, float* __restrict__ W)
{
    union SmemU {
        char  stage[2][24576];     // [buf][A 8KB | B 16KB]
        float Cs[NN][65];          // 33 KB epilogue half-tile
    };
    __shared__ SmemU u;
    __shared__ float tmi[NN];      // 128 text mask
    __shared__ float imj[256];     // 256 cols = four j's
    __shared__ float rowm[NN], rowsm[NN], rowred[NN];
    __shared__ float colred[LL];

    // 4x4 block-group swizzle for L2 locality
    const int bid = blockIdx.x;            // 0..1023
    const int grp = bid >> 4, idx = bid & 15;
    const int i   = (grp >> 2) * 4 + (idx >> 2);   // 0..63
    const int jj4 = (grp & 3) * 4 + (idx & 3);     // 0..15
    const int j0  = jj4 * 4;

    const int tid  = threadIdx.x;
    const int wave = tid >> 6;     // 0..7
    const int lane = tid & 63;
    const int quad = lane >> 4;    // k8 slot within chunk
    const int l15  = lane & 15;
    const int wr   = wave & 1;     // row group (64 rows)
    const int wc   = wave >> 1;    // col group (64 cols) == jh

    if (tid < NN)       tmi[tid] = tmask[i * NN + tid] ? 1.f : 0.f;
    else if (tid < 384) imj[tid - NN] = imask[j0 * LL + (tid - NN)] ? 1.f : 0.f;

    const unsigned short* pa = A + (size_t)i * NN * DD;
    const unsigned short* pb = B + (size_t)j0 * LL * DD;

    f32x4 acc[4][4];
    const f32x4 zf = {0.f, 0.f, 0.f, 0.f};
#pragma unroll
    for (int tr = 0; tr < 4; tr++)
#pragma unroll
        for (int tc = 0; tc < 4; tc++) acc[tr][tc] = zf;

    stage_chunk(pa, pb, 0, u.stage[0], wave, lane);
    __syncthreads();

    for (int c = 0; c < 24; c++) {
        if (c + 1 < 24)
            stage_chunk(pa, pb, (c + 1) << 5, u.stage[(c + 1) & 1], wave, lane);
        const char* Ab = u.stage[c & 1];
        const char* Bb = Ab + 8192;
        f16x8 af[4], bfr[4];
#pragma unroll
        for (int t = 0; t < 4; t++) {
            // A slot = quad*128 + row ; row = wr*64 + t*16 + l15
            af[t]  = *(const f16x8*)(Ab + ((quad << 7) + wr * 64 + t * 16 + l15) * 16);
            // B slot = quad*256 + col ; col = wc*64 + t*16 + l15
            bfr[t] = *(const f16x8*)(Bb + ((quad << 8) + wc * 64 + t * 16 + l15) * 16);
        }
#pragma unroll
        for (int tr = 0; tr < 4; tr++)
#pragma unroll
            for (int tc = 0; tc < 4; tc++)
                acc[tr][tc] = __builtin_amdgcn_mfma_f32_16x16x32_f16(
                    af[tr], bfr[tc], acc[tr][tc], 0, 0, 0);
        __syncthreads();
    }

    // ---- mask acc in place: vm = (tmask && imask && v!=0) ? v : NEG ----
    // C/D layout per 16x16 tile: row = quad*4 + rr, col = l15  (verified)
    float imv[4];
#pragma unroll
    for (int tc = 0; tc < 4; tc++) imv[tc] = imj[wc * 64 + tc * 16 + l15];
#pragma unroll
    for (int tr = 0; tr < 4; tr++) {
#pragma unroll
        for (int rr = 0; rr < 4; rr++) {
            float tmv = tmi[wr * 64 + tr * 16 + quad * 4 + rr];
#pragma unroll
            for (int tc = 0; tc < 4; tc++) {
                float v = acc[tr][tc][rr];
                bool keep = (tmv != 0.f) && (imv[tc] != 0.f) && (v != 0.f);
                acc[tr][tc][rr] = keep ? v : NEGV;
            }
        }
    }

    const bool diag = (jj4 == (i >> 2));
    const int  jhd  = i & 3;
    float* Cs = &u.Cs[0][0];       // [128][65]

    // ---- 4 passes, one jh (= one j) per pass ----
    for (int jh = 0; jh < 4; jh++) {
        __syncthreads();           // previous pass fully consumed
        if (wc == jh) {            // 2 waves materialize this 128x64 half
#pragma unroll
            for (int tr = 0; tr < 4; tr++)
#pragma unroll
                for (int tc = 0; tc < 4; tc++)
#pragma unroll
                    for (int rr = 0; rr < 4; rr++)
                        Cs[(wr * 64 + tr * 16 + quad * 4 + rr) * 65 + tc * 16 + l15]
                            = acc[tr][tc][rr];
        }
        __syncthreads();

        if (tid < 256) {
            // row softmax: 2 threads/row, 32 l each, shfl_xor(1) combine
            int row = tid >> 1, off = (tid & 1) * 32;
            const float* Cr = Cs + row * 65 + off;
            float m = -INFINITY;
            for (int l = 0; l < 32; l++) m = fmaxf(m, Cr[l]);
            m = fmaxf(m, __shfl_xor(m, 1));
            float ssum = 0.f, ws = 0.f;
            for (int l = 0; l < 32; l++) {
                float v = Cr[l];
                float e = __expf(v - m);
                ssum += e;
                ws += imj[jh * 64 + off + l] * e * v;
            }
            ssum += __shfl_xor(ssum, 1);
            ws   += __shfl_xor(ws, 1);
            if ((tid & 1) == 0) {
                rowm[row]  = m;
                rowsm[row] = ssum;
                rowred[row] = tmi[row] * (ws / ssum);
            }
        } else {
            // col softmax: 4 threads/col, 32 n each, shfl_xor(1,2) combine
            int u2 = tid - 256;
            int col = u2 >> 2, n0 = (u2 & 3) * 32;
            float m = -INFINITY;
            for (int n = 0; n < 32; n++) m = fmaxf(m, Cs[(n0 + n) * 65 + col]);
            m = fmaxf(m, __shfl_xor(m, 1));
            m = fmaxf(m, __shfl_xor(m, 2));
            float ssum = 0.f, ws = 0.f;
            for (int n = 0; n < 32; n++) {
                float v = Cs[(n0 + n) * 65 + col];
                float e = __expf(v - m);
                ssum += e;
                ws += tmi[n0 + n] * e * v;
            }
            ssum += __shfl_xor(ssum, 1); ssum += __shfl_xor(ssum, 2);
            ws   += __shfl_xor(ws, 1);   ws   += __shfl_xor(ws, 2);
            if ((u2 & 3) == 0) colred[col] = imj[jh * 64 + col] * (ws / ssum);
        }
        __syncthreads();

        // S[i][j0+jh] = (sum_n rowred + sum_l colred) / N
        if (tid < 64) {
            float p = rowred[tid] + rowred[64 + tid] + colred[tid];
#pragma unroll
            for (int off = 32; off; off >>= 1) p += __shfl_down(p, off);
            if (tid == 0) S[i * BSZ + j0 + jh] = p / (float)NN;
        } else if (diag && jh == jhd && tid >= 128 && tid < 384) {
            // W[i]: P = exp(vm - m)/ssum, 2 threads/row, reuses row stats
            int dn = tid - 128;
            int n = dn >> 1, l0 = (dn & 1) * 32;
            float m   = rowm[n];
            float inv = 1.f / rowsm[n];
            float* Wb = W + (size_t)i * LL * NN;
            for (int l = 0; l < 32; l++)
                Wb[(size_t)(l0 + l) * NN + n] = __expf(Cs[n * 65 + l0 + l] - m) * inv;
        }
    }
}

// ---------------------------------------------------------------------------
// Kernel 2: text_emb_i2s[b,n,d] = sum_l W[b][l][n] * img[b][l][d]
// ---------------------------------------------------------------------------
__global__ __launch_bounds__(256) void k_i2s(
    const float* __restrict__ W, const float* __restrict__ img,
    float* __restrict__ out)
{
    __shared__ float Ws[LL][16];   // 4 KB
    const int b  = blockIdx.x;
    const int ng = blockIdx.z * 16;
    const int d  = blockIdx.y * 256 + threadIdx.x;
    const float* Wb = W + (size_t)b * LL * NN;

    {   // stage W[l][ng..ng+15]: 1024 floats, 4 per thread
        int t4 = threadIdx.x * 4;
        int l = t4 >> 4, noff = t4 & 15;
        float4 w = *(const float4*)(Wb + (size_t)l * NN + ng + noff);
        Ws[l][noff + 0] = w.x; Ws[l][noff + 1] = w.y;
        Ws[l][noff + 2] = w.z; Ws[l][noff + 3] = w.w;
    }
    __syncthreads();

    const float* ib = img + (size_t)b * LL * DD;
    float* ob = out + 1 + (size_t)b * NN * DD + (size_t)ng * DD;  // slot 0 = loss

    float acc[16];
#pragma unroll
    for (int q = 0; q < 16; q++) acc[q] = 0.f;
    for (int l = 0; l < LL; l++) {
        float g = ib[(size_t)l * DD + d];
#pragma unroll
        for (int q = 0; q < 16; q++)
            acc[q] = fmaf(Ws[l][q], g, acc[q]);   // Ws read is broadcast
    }
#pragma unroll
    for (int q = 0; q < 16; q++)
        ob[(size_t)q * DD + d] = acc[q];
}

// ---------------------------------------------------------------------------
// Kernel 3: loss = -sum_i( 2*S[i,i] - lse_row_i(S) - lse_col_i(S) ) / B
// ---------------------------------------------------------------------------
__global__ void k_loss(const float* __restrict__ S, float* __restrict__ out)
{
    const int t = threadIdx.x;  // 0..63
    float diag = S[t * BSZ + t];
    float m1 = -INFINITY, m2 = -INFINITY;
    for (int jj = 0; jj < BSZ; jj++) {
        m1 = fmaxf(m1, S[t * BSZ + jj]);
        m2 = fmaxf(m2, S[jj * BSZ + t]);
    }
    float s1 = 0.f, s2 = 0.f;
    for (int jj = 0; jj < BSZ; jj++) {
        s1 += __expf(S[t * BSZ + jj] - m1);
        s2 += __expf(S[jj * BSZ + t] - m2);
    }
    float p = 2.f * diag - (m1 + logf(s1)) - (m2 + logf(s2));
#pragma unroll
    for (int off = 32; off; off >>= 1) p += __shfl_down(p, off);
    if (t == 0) out[0] = -p / (float)BSZ;
}

// ---------------------------------------------------------------------------
extern "C" void kernel_launch(void* const* d_in, const int* in_sizes, int n_in,
                              void* d_out, int out_size, void* d_ws, size_t ws_size,
                              hipStream_t stream)
{
    (void)in_sizes; (void)n_in; (void)out_size; (void)ws_size;
    const float* text = (const float*)d_in[0];   // [64,128,768] fp32
    const float* img  = (const float*)d_in[1];   // [64, 64,768] fp32
    const int*   tm   = (const int*)d_in[2];     // [64,128] int32
    const int*   im   = (const int*)d_in[3];     // [64, 64] int32
    float* out = (float*)d_out;                  // [1 + 64*128*768] fp32

    // workspace layout (bytes); total ~21 MB
    char* ws = (char*)d_ws;
    unsigned short* A = (unsigned short*)(ws);                   // 12.58 MB fp16
    unsigned short* B = (unsigned short*)(ws + 12582912);        //  6.29 MB fp16
    float* S = (float*)(ws + 18874368);                          // 16 KB
    float* W = (float*)(ws + 18890752);                          //  2 MB

    k_prep<<<(TQ + IQ) / 256, 256, 0, stream>>>(
        (const float4*)text, (const float4*)img, (ushort4*)A, (ushort4*)B);

    k_scores<<<BSZ * (BSZ / 4), 512, 0, stream>>>(A, B, tm, im, S, W);

    dim3 g2(BSZ, 3, 8);
    k_i2s<<<g2, 256, 0, stream>>>(W, img, out);

    k_loss<<<1, 64, 0, stream>>>(S, out);
}

// Round 6
// 282.102 us; speedup vs baseline: 2.1024x; 2.1024x over previous
//
#include <hip/hip_runtime.h>
#include <math.h>

// Problem constants (B, N, L, D) from the reference setup_inputs().
#define BSZ 64
#define NN  128
#define LL  64
#define DD  768
#define NEGV (-9e9f)

#define TQ (BSZ * NN * DD / 4)   // text float4 count  = 1572864
#define IQ (BSZ * LL * DD / 4)   // image float4 count =  786432

typedef _Float16 f16x8 __attribute__((ext_vector_type(8)));  // 8 f16 = 4 VGPRs
typedef __attribute__((ext_vector_type(4))) float f32x4;     // MFMA 16x16 accum

// async 16B global -> LDS (dest = wave-uniform base + lane*16)
__device__ __forceinline__ void gl_lds16(const void* g, void* l) {
    __builtin_amdgcn_global_load_lds(
        (const __attribute__((address_space(1))) void*)g,
        (__attribute__((address_space(3))) void*)l, 16, 0, 0);
}

// ---------------------------------------------------------------------------
// Kernel 0: fp32 -> fp16 (RTN).
// ---------------------------------------------------------------------------
__global__ __launch_bounds__(256) void k_prep(
    const float4* __restrict__ t4, const float4* __restrict__ g4,
    ushort4* __restrict__ A, ushort4* __restrict__ B)
{
    int id = blockIdx.x * 256 + threadIdx.x;
    const float4* src; ushort4* dst; int idx;
    if (id < TQ) { src = t4; dst = A; idx = id; }
    else         { src = g4; dst = B; idx = id - TQ; }
    float4 x = src[idx];
    _Float16 h0 = (_Float16)x.x, h1 = (_Float16)x.y;
    _Float16 h2 = (_Float16)x.z, h3 = (_Float16)x.w;
    ushort4 o;
    o.x = __builtin_bit_cast(unsigned short, h0);
    o.y = __builtin_bit_cast(unsigned short, h1);
    o.z = __builtin_bit_cast(unsigned short, h2);
    o.w = __builtin_bit_cast(unsigned short, h3);
    dst[idx] = o;
}

// ---------------------------------------------------------------------------
// Stage one BK=32 chunk into LDS, k8-major layout (conflict-free reads):
//   A region  8 KB: slot = k8*128 + r   (k8 in [0,4), r in [0,128))
//   B region 16 KB: slot = k8*256 + c   (c in [0,256) = 4 image rows)
// global_load_lds dest = wave-uniform base + lane*16; global src is per-lane,
// so src = row*DD + k0 + k8*8 realizes the k8-major layout with linear dest.
// 512 threads x 3 calls = 1536 x 16B slots = 24 KB.
// ---------------------------------------------------------------------------
__device__ __forceinline__ void stage_chunk(
    const unsigned short* __restrict__ pa, const unsigned short* __restrict__ pb,
    int k0, char* buf, int wave, int lane)
{
    int s = wave * 64 + lane;          // 0..511
    // A: slots 0..511
    {
        int k8 = s >> 7, r = s & 127;
        gl_lds16(pa + (size_t)r * DD + k0 + k8 * 8, buf + wave * 1024);
    }
    // B: slots 0..511
    {
        int k8 = s >> 8, c = s & 255;
        gl_lds16(pb + (size_t)c * DD + k0 + k8 * 8, buf + 8192 + wave * 1024);
    }
    // B: slots 512..1023
    {
        int s2 = s + 512;
        int k8 = s2 >> 8, c = s2 & 255;
        gl_lds16(pb + (size_t)c * DD + k0 + k8 * 8, buf + 16384 + wave * 1024);
    }
}

// ---------------------------------------------------------------------------
// Kernel 1: one block per (i, jj4) where jj4 covers j = {4jj4..4jj4+3}.
// C[128][256] = text[i] @ [image[j0..j0+3]]^T, fp16 MFMA, BK=32 chunks,
// double-buffered global_load_lds staging, 512 threads = 8 waves (2 row x
// 4 col groups, 64x64 per wave -> acc[4][4]).
// R3 fix: __launch_bounds__(512, 4) (NOT 6). min-waves/EU=6 capped VGPR at
// ~85 < the 96-reg accumulator+fragment footprint -> acc spilled to scratch
// (R3 counters: VGPR=40, WRITE_SIZE 1 GB, MfmaUtil 4%). Cap 128 fits the
// ~90-110 demand; 2 blocks/CU (16 waves, 50% occ), LDS 2x52.7 KB = 105 KB.
// Epilogue: stage buffers are dead -> reuse as Cs[128][65] (one 64-col jh
// half at a time, 4 passes); masked row/col softmax reductions; S + diag W.
// ---------------------------------------------------------------------------
__global__ __launch_bounds__(512, 4) void k_scores(
    const unsigned short* __restrict__ A, const unsigned short* __restrict__ B,
    const int* __restrict__ tmask, const int* __restrict__ imask,
    float* __restrict__ S, float* __restrict__ W)
{
    union SmemU {
        char  stage[2][24576];     // [buf][A 8KB | B 16KB]
        float Cs[NN][65];          // 33 KB epilogue half-tile
    };
    __shared__ SmemU u;
    __shared__ float tmi[NN];      // 128 text mask
    __shared__ float imj[256];     // 256 cols = four j's
    __shared__ float rowm[NN], rowsm[NN], rowred[NN];
    __shared__ float colred[LL];

    // 4x4 block-group swizzle for L2 locality
    const int bid = blockIdx.x;            // 0..1023
    const int grp = bid >> 4, idx = bid & 15;
    const int i   = (grp >> 2) * 4 + (idx >> 2);   // 0..63
    const int jj4 = (grp & 3) * 4 + (idx & 3);     // 0..15
    const int j0  = jj4 * 4;

    const int tid  = threadIdx.x;
    const int wave = tid >> 6;     // 0..7
    const int lane = tid & 63;
    const int quad = lane >> 4;    // k8 slot within chunk
    const int l15  = lane & 15;
    const int wr   = wave & 1;     // row group (64 rows)
    const int wc   = wave >> 1;    // col group (64 cols) == jh

    if (tid < NN)       tmi[tid] = tmask[i * NN + tid] ? 1.f : 0.f;
    else if (tid < 384) imj[tid - NN] = imask[j0 * LL + (tid - NN)] ? 1.f : 0.f;

    const unsigned short* pa = A + (size_t)i * NN * DD;
    const unsigned short* pb = B + (size_t)j0 * LL * DD;

    f32x4 acc[4][4];
    const f32x4 zf = {0.f, 0.f, 0.f, 0.f};
#pragma unroll
    for (int tr = 0; tr < 4; tr++)
#pragma unroll
        for (int tc = 0; tc < 4; tc++) acc[tr][tc] = zf;

    stage_chunk(pa, pb, 0, u.stage[0], wave, lane);
    __syncthreads();

    for (int c = 0; c < 24; c++) {
        if (c + 1 < 24)
            stage_chunk(pa, pb, (c + 1) << 5, u.stage[(c + 1) & 1], wave, lane);
        const char* Ab = u.stage[c & 1];
        const char* Bb = Ab + 8192;
        f16x8 af[4], bfr[4];
#pragma unroll
        for (int t = 0; t < 4; t++) {
            // A slot = quad*128 + row ; row = wr*64 + t*16 + l15
            af[t]  = *(const f16x8*)(Ab + ((quad << 7) + wr * 64 + t * 16 + l15) * 16);
            // B slot = quad*256 + col ; col = wc*64 + t*16 + l15
            bfr[t] = *(const f16x8*)(Bb + ((quad << 8) + wc * 64 + t * 16 + l15) * 16);
        }
#pragma unroll
        for (int tr = 0; tr < 4; tr++)
#pragma unroll
            for (int tc = 0; tc < 4; tc++)
                acc[tr][tc] = __builtin_amdgcn_mfma_f32_16x16x32_f16(
                    af[tr], bfr[tc], acc[tr][tc], 0, 0, 0);
        __syncthreads();
    }

    // ---- mask acc in place: vm = (tmask && imask && v!=0) ? v : NEG ----
    // C/D layout per 16x16 tile: row = quad*4 + rr, col = l15  (verified)
    float imv[4];
#pragma unroll
    for (int tc = 0; tc < 4; tc++) imv[tc] = imj[wc * 64 + tc * 16 + l15];
#pragma unroll
    for (int tr = 0; tr < 4; tr++) {
#pragma unroll
        for (int rr = 0; rr < 4; rr++) {
            float tmv = tmi[wr * 64 + tr * 16 + quad * 4 + rr];
#pragma unroll
            for (int tc = 0; tc < 4; tc++) {
                float v = acc[tr][tc][rr];
                bool keep = (tmv != 0.f) && (imv[tc] != 0.f) && (v != 0.f);
                acc[tr][tc][rr] = keep ? v : NEGV;
            }
        }
    }

    const bool diag = (jj4 == (i >> 2));
    const int  jhd  = i & 3;
    float* Cs = &u.Cs[0][0];       // [128][65]

    // ---- 4 passes, one jh (= one j) per pass ----
    for (int jh = 0; jh < 4; jh++) {
        __syncthreads();           // previous pass fully consumed
        if (wc == jh) {            // 2 waves materialize this 128x64 half
#pragma unroll
            for (int tr = 0; tr < 4; tr++)
#pragma unroll
                for (int tc = 0; tc < 4; tc++)
#pragma unroll
                    for (int rr = 0; rr < 4; rr++)
                        Cs[(wr * 64 + tr * 16 + quad * 4 + rr) * 65 + tc * 16 + l15]
                            = acc[tr][tc][rr];
        }
        __syncthreads();

        if (tid < 256) {
            // row softmax: 2 threads/row, 32 l each, shfl_xor(1) combine
            int row = tid >> 1, off = (tid & 1) * 32;
            const float* Cr = Cs + row * 65 + off;
            float m = -INFINITY;
            for (int l = 0; l < 32; l++) m = fmaxf(m, Cr[l]);
            m = fmaxf(m, __shfl_xor(m, 1));
            float ssum = 0.f, ws = 0.f;
            for (int l = 0; l < 32; l++) {
                float v = Cr[l];
                float e = __expf(v - m);
                ssum += e;
                ws += imj[jh * 64 + off + l] * e * v;
            }
            ssum += __shfl_xor(ssum, 1);
            ws   += __shfl_xor(ws, 1);
            if ((tid & 1) == 0) {
                rowm[row]  = m;
                rowsm[row] = ssum;
                rowred[row] = tmi[row] * (ws / ssum);
            }
        } else {
            // col softmax: 4 threads/col, 32 n each, shfl_xor(1,2) combine
            int u2 = tid - 256;
            int col = u2 >> 2, n0 = (u2 & 3) * 32;
            float m = -INFINITY;
            for (int n = 0; n < 32; n++) m = fmaxf(m, Cs[(n0 + n) * 65 + col]);
            m = fmaxf(m, __shfl_xor(m, 1));
            m = fmaxf(m, __shfl_xor(m, 2));
            float ssum = 0.f, ws = 0.f;
            for (int n = 0; n < 32; n++) {
                float v = Cs[(n0 + n) * 65 + col];
                float e = __expf(v - m);
                ssum += e;
                ws += tmi[n0 + n] * e * v;
            }
            ssum += __shfl_xor(ssum, 1); ssum += __shfl_xor(ssum, 2);
            ws   += __shfl_xor(ws, 1);   ws   += __shfl_xor(ws, 2);
            if ((u2 & 3) == 0) colred[col] = imj[jh * 64 + col] * (ws / ssum);
        }
        __syncthreads();

        // S[i][j0+jh] = (sum_n rowred + sum_l colred) / N
        if (tid < 64) {
            float p = rowred[tid] + rowred[64 + tid] + colred[tid];
#pragma unroll
            for (int off = 32; off; off >>= 1) p += __shfl_down(p, off);
            if (tid == 0) S[i * BSZ + j0 + jh] = p / (float)NN;
        } else if (diag && jh == jhd && tid >= 128 && tid < 384) {
            // W[i]: P = exp(vm - m)/ssum, 2 threads/row, reuses row stats
            int dn = tid - 128;
            int n = dn >> 1, l0 = (dn & 1) * 32;
            float m   = rowm[n];
            float inv = 1.f / rowsm[n];
            float* Wb = W + (size_t)i * LL * NN;
            for (int l = 0; l < 32; l++)
                Wb[(size_t)(l0 + l) * NN + n] = __expf(Cs[n * 65 + l0 + l] - m) * inv;
        }
    }
}

// ---------------------------------------------------------------------------
// Kernel 2: text_emb_i2s[b,n,d] = sum_l W[b][l][n] * img[b][l][d]
// ---------------------------------------------------------------------------
__global__ __launch_bounds__(256) void k_i2s(
    const float* __restrict__ W, const float* __restrict__ img,
    float* __restrict__ out)
{
    __shared__ float Ws[LL][16];   // 4 KB
    const int b  = blockIdx.x;
    const int ng = blockIdx.z * 16;
    const int d  = blockIdx.y * 256 + threadIdx.x;
    const float* Wb = W + (size_t)b * LL * NN;

    {   // stage W[l][ng..ng+15]: 1024 floats, 4 per thread
        int t4 = threadIdx.x * 4;
        int l = t4 >> 4, noff = t4 & 15;
        float4 w = *(const float4*)(Wb + (size_t)l * NN + ng + noff);
        Ws[l][noff + 0] = w.x; Ws[l][noff + 1] = w.y;
        Ws[l][noff + 2] = w.z; Ws[l][noff + 3] = w.w;
    }
    __syncthreads();

    const float* ib = img + (size_t)b * LL * DD;
    float* ob = out + 1 + (size_t)b * NN * DD + (size_t)ng * DD;  // slot 0 = loss

    float acc[16];
#pragma unroll
    for (int q = 0; q < 16; q++) acc[q] = 0.f;
    for (int l = 0; l < LL; l++) {
        float g = ib[(size_t)l * DD + d];
#pragma unroll
        for (int q = 0; q < 16; q++)
            acc[q] = fmaf(Ws[l][q], g, acc[q]);   // Ws read is broadcast
    }
#pragma unroll
    for (int q = 0; q < 16; q++)
        ob[(size_t)q * DD + d] = acc[q];
}

// ---------------------------------------------------------------------------
// Kernel 3: loss = -sum_i( 2*S[i,i] - lse_row_i(S) - lse_col_i(S) ) / B
// ---------------------------------------------------------------------------
__global__ void k_loss(const float* __restrict__ S, float* __restrict__ out)
{
    const int t = threadIdx.x;  // 0..63
    float diag = S[t * BSZ + t];
    float m1 = -INFINITY, m2 = -INFINITY;
    for (int jj = 0; jj < BSZ; jj++) {
        m1 = fmaxf(m1, S[t * BSZ + jj]);
        m2 = fmaxf(m2, S[jj * BSZ + t]);
    }
    float s1 = 0.f, s2 = 0.f;
    for (int jj = 0; jj < BSZ; jj++) {
        s1 += __expf(S[t * BSZ + jj] - m1);
        s2 += __expf(S[jj * BSZ + t] - m2);
    }
    float p = 2.f * diag - (m1 + logf(s1)) - (m2 + logf(s2));
#pragma unroll
    for (int off = 32; off; off >>= 1) p += __shfl_down(p, off);
    if (t == 0) out[0] = -p / (float)BSZ;
}

// ---------------------------------------------------------------------------
extern "C" void kernel_launch(void* const* d_in, const int* in_sizes, int n_in,
                              void* d_out, int out_size, void* d_ws, size_t ws_size,
                              hipStream_t stream)
{
    (void)in_sizes; (void)n_in; (void)out_size; (void)ws_size;
    const float* text = (const float*)d_in[0];   // [64,128,768] fp32
    const float* img  = (const float*)d_in[1];   // [64, 64,768] fp32
    const int*   tm   = (const int*)d_in[2];     // [64,128] int32
    const int*   im   = (const int*)d_in[3];     // [64, 64] int32
    float* out = (float*)d_out;                  // [1 + 64*128*768] fp32

    // workspace layout (bytes); total ~21 MB
    char* ws = (char*)d_ws;
    unsigned short* A = (unsigned short*)(ws);                   // 12.58 MB fp16
    unsigned short* B = (unsigned short*)(ws + 12582912);        //  6.29 MB fp16
    float* S = (float*)(ws + 18874368);                          // 16 KB
    float* W = (float*)(ws + 18890752);                          //  2 MB

    k_prep<<<(TQ + IQ) / 256, 256, 0, stream>>>(
        (const float4*)text, (const float4*)img, (ushort4*)A, (ushort4*)B);

    k_scores<<<BSZ * (BSZ / 4), 512, 0, stream>>>(A, B, tm, im, S, W);

    dim3 g2(BSZ, 3, 8);
    k_i2s<<<g2, 256, 0, stream>>>(W, img, out);

    k_loss<<<1, 64, 0, stream>>>(S, out);
}

// Round 7
// 242.766 us; speedup vs baseline: 2.4431x; 1.1620x over previous
//
#include <hip/hip_runtime.h>
#include <math.h>

// Problem constants (B, N, L, D) from the reference setup_inputs().
#define BSZ 64
#define NN  128
#define LL  64
#define DD  768
#define NEGV (-9e9f)

#define TQ (BSZ * NN * DD / 4)   // text float4 count  = 1572864
#define IQ (BSZ * LL * DD / 4)   // image float4 count =  786432

typedef _Float16 f16x8 __attribute__((ext_vector_type(8)));  // 8 f16 = 4 VGPRs
typedef __attribute__((ext_vector_type(4))) float f32x4;     // MFMA 16x16 accum

// async 16B global -> LDS (dest = wave-uniform base + lane*16)
__device__ __forceinline__ void gl_lds16(const void* g, void* l) {
    __builtin_amdgcn_global_load_lds(
        (const __attribute__((address_space(1))) void*)g,
        (__attribute__((address_space(3))) void*)l, 16, 0, 0);
}

// ---------------------------------------------------------------------------
// Kernel 0: fp32 -> fp16 (RTN).
// ---------------------------------------------------------------------------
__global__ __launch_bounds__(256) void k_prep(
    const float4* __restrict__ t4, const float4* __restrict__ g4,
    ushort4* __restrict__ A, ushort4* __restrict__ B)
{
    int id = blockIdx.x * 256 + threadIdx.x;
    const float4* src; ushort4* dst; int idx;
    if (id < TQ) { src = t4; dst = A; idx = id; }
    else         { src = g4; dst = B; idx = id - TQ; }
    float4 x = src[idx];
    _Float16 h0 = (_Float16)x.x, h1 = (_Float16)x.y;
    _Float16 h2 = (_Float16)x.z, h3 = (_Float16)x.w;
    ushort4 o;
    o.x = __builtin_bit_cast(unsigned short, h0);
    o.y = __builtin_bit_cast(unsigned short, h1);
    o.z = __builtin_bit_cast(unsigned short, h2);
    o.w = __builtin_bit_cast(unsigned short, h3);
    dst[idx] = o;
}

// ---------------------------------------------------------------------------
// Stage one BK=32 chunk (16 KB) into LDS, k8-major layout (conflict-free):
//   A region 8 KB: slot = k8*128 + r   (k8 in [0,4), r = text row in [0,128))
//   B region 8 KB: slot = k8*128 + c   (c = col in [0,128) = 2 image rows)
// global_load_lds dest = wave-uniform base + lane*16; global src is per-lane,
// so src = row*DD + k0 + k8*8 realizes the k8-major layout with linear dest.
// 256 threads x 4 calls = 1024 x 16B slots = 16 KB.
// ---------------------------------------------------------------------------
__device__ __forceinline__ void stage_chunk(
    const unsigned short* __restrict__ pa, const unsigned short* __restrict__ pb,
    int k0, char* buf, int wave, int lane)
{
#pragma unroll
    for (int c = 0; c < 2; c++) {
        int s  = c * 256 + wave * 64 + lane;   // 0..511
        int k8 = s >> 7, r = s & 127;
        gl_lds16(pa + (size_t)r * DD + k0 + k8 * 8, buf + c * 4096 + wave * 1024);
        gl_lds16(pb + (size_t)r * DD + k0 + k8 * 8, buf + 8192 + c * 4096 + wave * 1024);
    }
}

// ---------------------------------------------------------------------------
// Kernel 1: one block per (i, jj), jj covers j = {2jj, 2jj+1} (2048 blocks).
// C[128][128] = text[i] @ [image[j0]; image[j1]]^T, fp16 MFMA, BK=32 x 24
// chunks, double-buffered global_load_lds, 256 threads = 4 waves (2 row x
// 2 col groups, 64x64/wave -> acc[4][4]; this shape measured 88 VGPR in R1,
// no spill).
// R6: occupancy via LDS, not block size. R5's 512t/128-reg cap still spilled
// (VGPR=64 arch+64 acc, WRITE 127 MB). Here: BK=32 stage (2x16 KB) unioned
// with Cs[128][65] half-tile (33.3 KB) -> 36.1 KB LDS -> 4 blocks/CU
// (16 waves, 50% occ) at the proven 256-thread shape.
// Epilogue: 2 jh-passes (R5-verified structure): masked row/col softmax,
// S + diagonal W reusing row stats.
// ---------------------------------------------------------------------------
__global__ __launch_bounds__(256, 2) void k_scores(
    const unsigned short* __restrict__ A, const unsigned short* __restrict__ B,
    const int* __restrict__ tmask, const int* __restrict__ imask,
    float* __restrict__ S, float* __restrict__ W)
{
    union SmemU {
        char  stage[2][16384];     // [buf][A 8KB | B 8KB]
        float Cs[NN][65];          // 33.3 KB epilogue half-tile
    };
    __shared__ SmemU u;
    __shared__ float tmi[NN];      // 128 text mask
    __shared__ float imj[NN];      // 128 cols = two j's
    __shared__ float rowm[NN], rowsm[NN], rowred[NN];
    __shared__ float colred[LL];

    // 4x4 block-group swizzle for L2 locality
    const int bid = blockIdx.x;            // 0..2047
    const int grp = bid >> 4, idx = bid & 15;
    const int i  = (grp >> 3) * 4 + (idx >> 2);   // 0..63
    const int jj = (grp & 7) * 4 + (idx & 3);     // 0..31
    const int j0 = jj * 2;

    const int tid  = threadIdx.x;
    const int wave = tid >> 6;     // 0..3
    const int lane = tid & 63;
    const int quad = lane >> 4;    // k8 slot within chunk
    const int l15  = lane & 15;
    const int rh   = wave & 1;     // row group (64 rows)
    const int ch   = wave >> 1;    // col group (64 cols) == jh

    if (tid < NN) {
        tmi[tid] = tmask[i * NN + tid] ? 1.f : 0.f;
        imj[tid] = imask[j0 * LL + tid] ? 1.f : 0.f;   // two j's contiguous
    }

    const unsigned short* pa = A + (size_t)i * NN * DD;
    const unsigned short* pb = B + (size_t)j0 * LL * DD;

    f32x4 acc[4][4];
    const f32x4 zf = {0.f, 0.f, 0.f, 0.f};
#pragma unroll
    for (int tr = 0; tr < 4; tr++)
#pragma unroll
        for (int tc = 0; tc < 4; tc++) acc[tr][tc] = zf;

    stage_chunk(pa, pb, 0, u.stage[0], wave, lane);
    __syncthreads();

    for (int c = 0; c < 24; c++) {
        if (c + 1 < 24)
            stage_chunk(pa, pb, (c + 1) << 5, u.stage[(c + 1) & 1], wave, lane);
        const char* Ab = u.stage[c & 1];
        const char* Bb = Ab + 8192;
        f16x8 af[4], bfr[4];
#pragma unroll
        for (int t = 0; t < 4; t++) {
            // A slot = quad*128 + row ; row = rh*64 + t*16 + l15
            af[t]  = *(const f16x8*)(Ab + ((quad << 7) + rh * 64 + t * 16 + l15) * 16);
            // B slot = quad*128 + col ; col = ch*64 + t*16 + l15
            bfr[t] = *(const f16x8*)(Bb + ((quad << 7) + ch * 64 + t * 16 + l15) * 16);
        }
#pragma unroll
        for (int tr = 0; tr < 4; tr++)
#pragma unroll
            for (int tc = 0; tc < 4; tc++)
                acc[tr][tc] = __builtin_amdgcn_mfma_f32_16x16x32_f16(
                    af[tr], bfr[tc], acc[tr][tc], 0, 0, 0);
        __syncthreads();
    }

    // ---- mask acc in place: vm = (tmask && imask && v!=0) ? v : NEG ----
    // C/D layout per 16x16 tile: row = quad*4 + rr, col = l15  (verified)
    float imv[4];
#pragma unroll
    for (int tc = 0; tc < 4; tc++) imv[tc] = imj[ch * 64 + tc * 16 + l15];
#pragma unroll
    for (int tr = 0; tr < 4; tr++) {
#pragma unroll
        for (int rr = 0; rr < 4; rr++) {
            float tmv = tmi[rh * 64 + tr * 16 + quad * 4 + rr];
#pragma unroll
            for (int tc = 0; tc < 4; tc++) {
                float v = acc[tr][tc][rr];
                bool keep = (tmv != 0.f) && (imv[tc] != 0.f) && (v != 0.f);
                acc[tr][tc][rr] = keep ? v : NEGV;
            }
        }
    }

    const bool diag = (jj == (i >> 1));
    const int  jhd  = i & 1;
    float* Cs = &u.Cs[0][0];       // [128][65]

    // ---- 2 passes, one jh (= one j) per pass ----
    for (int jh = 0; jh < 2; jh++) {
        __syncthreads();           // previous pass fully consumed (incl. W read)
        if (ch == jh) {            // 2 waves materialize this 128x64 half
#pragma unroll
            for (int tr = 0; tr < 4; tr++)
#pragma unroll
                for (int tc = 0; tc < 4; tc++)
#pragma unroll
                    for (int rr = 0; rr < 4; rr++)
                        Cs[(rh * 64 + tr * 16 + quad * 4 + rr) * 65 + tc * 16 + l15]
                            = acc[tr][tc][rr];
        }
        __syncthreads();

        // row softmax: 2 threads/row, 32 l each, shfl_xor(1) combine
        {
            int row = tid >> 1, off = (tid & 1) * 32;
            const float* Cr = Cs + row * 65 + off;
            float m = -INFINITY;
            for (int l = 0; l < 32; l++) m = fmaxf(m, Cr[l]);
            m = fmaxf(m, __shfl_xor(m, 1));
            float ssum = 0.f, ws = 0.f;
            for (int l = 0; l < 32; l++) {
                float v = Cr[l];
                float e = __expf(v - m);      // all-NEG row -> uniform
                ssum += e;
                ws += imj[jh * 64 + off + l] * e * v;
            }
            ssum += __shfl_xor(ssum, 1);
            ws   += __shfl_xor(ws, 1);
            if ((tid & 1) == 0) {
                rowm[row]  = m;
                rowsm[row] = ssum;
                rowred[row] = tmi[row] * (ws / ssum);
            }
        }
        __syncthreads();

        // col softmax: 4 threads/col, 32 n each, shfl_xor(1,2) combine
        {
            int col = tid >> 2, n0 = (tid & 3) * 32;
            float m = -INFINITY;
            for (int n = 0; n < 32; n++) m = fmaxf(m, Cs[(n0 + n) * 65 + col]);
            m = fmaxf(m, __shfl_xor(m, 1));
            m = fmaxf(m, __shfl_xor(m, 2));
            float ssum = 0.f, ws = 0.f;
            for (int n = 0; n < 32; n++) {
                float v = Cs[(n0 + n) * 65 + col];
                float e = __expf(v - m);
                ssum += e;
                ws += tmi[n0 + n] * e * v;
            }
            ssum += __shfl_xor(ssum, 1); ssum += __shfl_xor(ssum, 2);
            ws   += __shfl_xor(ws, 1);   ws   += __shfl_xor(ws, 2);
            if ((tid & 3) == 0) colred[col] = imj[jh * 64 + col] * (ws / ssum);
        }
        __syncthreads();

        // diagonal W (32/2048 blocks): all 256 threads, reuses row stats
        if (diag && jh == jhd) {
            int n = tid >> 1, l0 = (tid & 1) * 32;
            float m   = rowm[n];
            float inv = 1.f / rowsm[n];
            float* Wb = W + (size_t)i * LL * NN;
            for (int l = 0; l < 32; l++)
                Wb[(size_t)(l0 + l) * NN + n] = __expf(Cs[n * 65 + l0 + l] - m) * inv;
        }

        // S[i][j0+jh] = (sum_n rowred + sum_l colred) / N
        if (tid < 64) {
            float p = rowred[tid] + rowred[64 + tid] + colred[tid];
#pragma unroll
            for (int off = 32; off; off >>= 1) p += __shfl_down(p, off);
            if (tid == 0) S[i * BSZ + j0 + jh] = p / (float)NN;
        }
    }
}

// ---------------------------------------------------------------------------
// Kernel 2: text_emb_i2s[b,n,d] = sum_l W[b][l][n] * img[b][l][d]
// ---------------------------------------------------------------------------
__global__ __launch_bounds__(256) void k_i2s(
    const float* __restrict__ W, const float* __restrict__ img,
    float* __restrict__ out)
{
    __shared__ float Ws[LL][16];   // 4 KB
    const int b  = blockIdx.x;
    const int ng = blockIdx.z * 16;
    const int d  = blockIdx.y * 256 + threadIdx.x;
    const float* Wb = W + (size_t)b * LL * NN;

    {   // stage W[l][ng..ng+15]: 1024 floats, 4 per thread
        int t4 = threadIdx.x * 4;
        int l = t4 >> 4, noff = t4 & 15;
        float4 w = *(const float4*)(Wb + (size_t)l * NN + ng + noff);
        Ws[l][noff + 0] = w.x; Ws[l][noff + 1] = w.y;
        Ws[l][noff + 2] = w.z; Ws[l][noff + 3] = w.w;
    }
    __syncthreads();

    const float* ib = img + (size_t)b * LL * DD;
    float* ob = out + 1 + (size_t)b * NN * DD + (size_t)ng * DD;  // slot 0 = loss

    float acc[16];
#pragma unroll
    for (int q = 0; q < 16; q++) acc[q] = 0.f;
    for (int l = 0; l < LL; l++) {
        float g = ib[(size_t)l * DD + d];
#pragma unroll
        for (int q = 0; q < 16; q++)
            acc[q] = fmaf(Ws[l][q], g, acc[q]);   // Ws read is broadcast
    }
#pragma unroll
    for (int q = 0; q < 16; q++)
        ob[(size_t)q * DD + d] = acc[q];
}

// ---------------------------------------------------------------------------
// Kernel 3: loss = -sum_i( 2*S[i,i] - lse_row_i(S) - lse_col_i(S) ) / B
// ---------------------------------------------------------------------------
__global__ void k_loss(const float* __restrict__ S, float* __restrict__ out)
{
    const int t = threadIdx.x;  // 0..63
    float diag = S[t * BSZ + t];
    float m1 = -INFINITY, m2 = -INFINITY;
    for (int jj = 0; jj < BSZ; jj++) {
        m1 = fmaxf(m1, S[t * BSZ + jj]);
        m2 = fmaxf(m2, S[jj * BSZ + t]);
    }
    float s1 = 0.f, s2 = 0.f;
    for (int jj = 0; jj < BSZ; jj++) {
        s1 += __expf(S[t * BSZ + jj] - m1);
        s2 += __expf(S[jj * BSZ + t] - m2);
    }
    float p = 2.f * diag - (m1 + logf(s1)) - (m2 + logf(s2));
#pragma unroll
    for (int off = 32; off; off >>= 1) p += __shfl_down(p, off);
    if (t == 0) out[0] = -p / (float)BSZ;
}

// ---------------------------------------------------------------------------
extern "C" void kernel_launch(void* const* d_in, const int* in_sizes, int n_in,
                              void* d_out, int out_size, void* d_ws, size_t ws_size,
                              hipStream_t stream)
{
    (void)in_sizes; (void)n_in; (void)out_size; (void)ws_size;
    const float* text = (const float*)d_in[0];   // [64,128,768] fp32
    const float* img  = (const float*)d_in[1];   // [64, 64,768] fp32
    const int*   tm   = (const int*)d_in[2];     // [64,128] int32
    const int*   im   = (const int*)d_in[3];     // [64, 64] int32
    float* out = (float*)d_out;                  // [1 + 64*128*768] fp32

    // workspace layout (bytes); total ~21 MB
    char* ws = (char*)d_ws;
    unsigned short* A = (unsigned short*)(ws);                   // 12.58 MB fp16
    unsigned short* B = (unsigned short*)(ws + 12582912);        //  6.29 MB fp16
    float* S = (float*)(ws + 18874368);                          // 16 KB
    float* W = (float*)(ws + 18890752);                          //  2 MB

    k_prep<<<(TQ + IQ) / 256, 256, 0, stream>>>(
        (const float4*)text, (const float4*)img, (ushort4*)A, (ushort4*)B);

    k_scores<<<BSZ * (BSZ / 2), 256, 0, stream>>>(A, B, tm, im, S, W);

    dim3 g2(BSZ, 3, 8);
    k_i2s<<<g2, 256, 0, stream>>>(W, img, out);

    k_loss<<<1, 64, 0, stream>>>(S, out);
}

// Round 8
// 184.469 us; speedup vs baseline: 3.2151x; 1.3160x over previous
//
#include <hip/hip_runtime.h>
#include <math.h>

// Problem constants (B, N, L, D) from the reference setup_inputs().
#define BSZ 64
#define NN  128
#define LL  64
#define DD  768
#define NEGV (-9e9f)

#define TQ (BSZ * NN * DD / 4)   // text float4 count  = 1572864
#define IQ (BSZ * LL * DD / 4)   // image float4 count =  786432

typedef _Float16 f16x8 __attribute__((ext_vector_type(8)));  // 8 f16 = 4 VGPRs
typedef __attribute__((ext_vector_type(4))) float f32x4;     // MFMA 16x16 accum

// async 16B global -> LDS (dest = wave-uniform base + lane*16)
__device__ __forceinline__ void gl_lds16(const void* g, void* l) {
    __builtin_amdgcn_global_load_lds(
        (const __attribute__((address_space(1))) void*)g,
        (__attribute__((address_space(3))) void*)l, 16, 0, 0);
}

// ---------------------------------------------------------------------------
// Kernel 0: fp32 -> fp16 (RTN). Error 2^-11 relative; N(0,1) inputs.
// ---------------------------------------------------------------------------
__global__ __launch_bounds__(256) void k_prep(
    const float4* __restrict__ t4, const float4* __restrict__ g4,
    ushort4* __restrict__ A, ushort4* __restrict__ B)
{
    int id = blockIdx.x * 256 + threadIdx.x;
    const float4* src; ushort4* dst; int idx;
    if (id < TQ) { src = t4; dst = A; idx = id; }
    else         { src = g4; dst = B; idx = id - TQ; }
    float4 x = src[idx];
    _Float16 h0 = (_Float16)x.x, h1 = (_Float16)x.y;
    _Float16 h2 = (_Float16)x.z, h3 = (_Float16)x.w;
    ushort4 o;
    o.x = __builtin_bit_cast(unsigned short, h0);
    o.y = __builtin_bit_cast(unsigned short, h1);
    o.z = __builtin_bit_cast(unsigned short, h2);
    o.w = __builtin_bit_cast(unsigned short, h3);
    dst[idx] = o;
}

// ---------------------------------------------------------------------------
// Stage one 32 KB chunk (A: 128 rows x 64 k f16, B: 128 rows x 64 k) into LDS.
// LDS slot for (r, k8): r*8 + (k8 ^ (r&7)), 16B per slot (XOR bank swizzle).
// global_load_lds dest = wave-uniform base + lane*16; slot index is linear
// in (call, wave, lane): slot = c*256 + wave*64 + lane.
// [R7 lesson: this BK=64 / 12-chunk structure measured 87 us; BK=32/24-chunk
//  variant measured 160 us (2x barrier drains, 8x bank conflicts). Keep.]
// ---------------------------------------------------------------------------
__device__ __forceinline__ void stage_chunk(
    const unsigned short* __restrict__ pa, const unsigned short* __restrict__ pb,
    int k0, char* buf, int wave, int lane)
{
    int rsub = lane >> 3;     // 0..7
    int k8s  = lane & 7;
#pragma unroll
    for (int c = 0; c < 4; c++) {
        int r  = c * 32 + wave * 8 + rsub;
        int k8 = k8s ^ (r & 7);
        gl_lds16(pa + (size_t)r * DD + k0 + k8 * 8, buf + c * 4096 + wave * 1024);
        gl_lds16(pb + (size_t)r * DD + k0 + k8 * 8, buf + 16384 + c * 4096 + wave * 1024);
    }
}

// ---------------------------------------------------------------------------
// Kernel 1: one block per (i, jj) where jj covers j = {2jj, 2jj+1}.
// C[128][128] = text[i] @ [image[j0]; image[j1]]^T, single-pass fp16 MFMA,
// LDS-staged via global_load_lds, double-buffered, 12 chunks of BK=64.
// Measured (R2): 87.1 us, MfmaUtil 24%, occ 20%, VGPR 88, FETCH 31 MB.
// Occupancy-via-LDS attempts (R5-R7) refuted: measured occupancy stays
// ~20-22% regardless of LDS 36-74 KB; BK=32 regressed 2x. This 2-block/CU
// 2-phase structure is at its known ceiling.
// ---------------------------------------------------------------------------
__global__ __launch_bounds__(256, 2) void k_scores(
    const unsigned short* __restrict__ A, const unsigned short* __restrict__ B,
    const int* __restrict__ tmask, const int* __restrict__ imask,
    float* __restrict__ S, float* __restrict__ W)
{
    union SmemU {
        char  stage[2][32768];     // [buf][A 16KB | B 16KB]
        float Cs[NN][129];         // 66 KB epilogue tile (stride 129: 2-way free)
    };
    __shared__ SmemU u;
    __shared__ float tmi[NN];
    __shared__ float imj[NN];      // 128 cols = two j's
    __shared__ float rowred[256];
    __shared__ float colred[NN];
    __shared__ float rowm[256], rowsm[256];          // phase-1 row stats stash
    __shared__ float colm[256], colp1[256], colp2[256];  // phase-2 partials

    // 4x4 block-group swizzle for L2 locality (~1.6 MB working set / group)
    const int bid = blockIdx.x;
    const int grp = bid >> 4, idx = bid & 15;
    const int i  = (grp >> 3) * 4 + (idx >> 2);   // 0..63
    const int jj = (grp & 7) * 4 + (idx & 3);     // 0..31
    const int j0 = jj * 2;

    const int tid  = threadIdx.x;
    const int wave = tid >> 6;
    const int lane = tid & 63;
    const int quad = lane >> 4;
    const int l15  = lane & 15;
    const int rh   = wave & 1;     // row half (64 rows)
    const int ch   = wave >> 1;    // col half (64 cols)

    if (tid < NN) {
        tmi[tid] = tmask[i * NN + tid] ? 1.f : 0.f;
        imj[tid] = imask[j0 * LL + tid] ? 1.f : 0.f;   // two j's contiguous
    }

    const unsigned short* pa = A + (size_t)i * NN * DD;
    const unsigned short* pb = B + (size_t)j0 * LL * DD;

    f32x4 acc[4][4];
    const f32x4 zf = {0.f, 0.f, 0.f, 0.f};
#pragma unroll
    for (int tr = 0; tr < 4; tr++)
#pragma unroll
        for (int tc = 0; tc < 4; tc++) acc[tr][tc] = zf;

    stage_chunk(pa, pb, 0, u.stage[0], wave, lane);
    __syncthreads();

    for (int c = 0; c < 12; c++) {
        if (c + 1 < 12)
            stage_chunk(pa, pb, (c + 1) << 6, u.stage[(c + 1) & 1], wave, lane);
        const char* Ab = u.stage[c & 1];
        const char* Bb = Ab + 16384;
#pragma unroll
        for (int s = 0; s < 2; s++) {
            int k8q = s * 4 + quad;
            int sw  = k8q ^ (l15 & 7);
            f16x8 af[4], bfr[4];
#pragma unroll
            for (int t = 0; t < 4; t++) {
                int row = rh * 64 + t * 16 + l15;
                af[t]  = *(const f16x8*)(Ab + ((row << 3) + sw) * 16);
                int col = ch * 64 + t * 16 + l15;
                bfr[t] = *(const f16x8*)(Bb + ((col << 3) + sw) * 16);
            }
#pragma unroll
            for (int tr = 0; tr < 4; tr++)
#pragma unroll
                for (int tc = 0; tc < 4; tc++)
                    acc[tr][tc] = __builtin_amdgcn_mfma_f32_16x16x32_f16(
                        af[tr], bfr[tc], acc[tr][tc], 0, 0, 0);
        }
        __syncthreads();
    }

    // masked att -> Cs.  att = (mask && dot != 0) ? dot : NEG
    // C/D layout per 16x16 tile: row = quad*4 + rr, col = l15
#pragma unroll
    for (int tr = 0; tr < 4; tr++) {
        int rb = rh * 64 + tr * 16 + quad * 4;
#pragma unroll
        for (int tc = 0; tc < 4; tc++) {
            int col = ch * 64 + tc * 16 + l15;
            float im = imj[col];
#pragma unroll
            for (int rr = 0; rr < 4; rr++) {
                int row = rb + rr;
                float v = acc[tr][tc][rr];
                bool keep = (tmi[row] != 0.f) && (im != 0.f) && (v != 0.f);
                u.Cs[row][col] = keep ? v : NEGV;
            }
        }
    }
    __syncthreads();

    // phase 1: row softmax over l for each (jh, n) -- all 256 threads
    {
        int jh = tid >> 7, n = tid & 127;
        const float* Crow = &u.Cs[n][jh * 64];
        float m = -INFINITY;
        for (int l = 0; l < LL; l++) m = fmaxf(m, Crow[l]);
        float ssum = 0.f, ws = 0.f;
        for (int l = 0; l < LL; l++) {
            float v = Crow[l];
            float e = __expf(v - m);      // all-NEG row -> uniform
            ssum += e;
            ws += imj[jh * 64 + l] * e * v;
        }
        rowm[tid] = m;                    // stash for diagonal W (bit-exact)
        rowsm[tid] = ssum;
        rowred[tid] = tmi[n] * (ws / ssum);
    }
    __syncthreads();

    // phase 2: col softmax, ALL 256 threads, 2 per column (split over n-halves)
    {
        int c  = tid & 127;              // column 0..127
        int n0 = (tid >> 7) * 64;        // row half start
        float m = -INFINITY;
        for (int n = n0; n < n0 + 64; n++) m = fmaxf(m, u.Cs[n][c]);
        colm[tid] = m;
        __syncthreads();
        m = fmaxf(colm[tid], colm[tid ^ 128]);
        float ssum = 0.f, ws = 0.f;
        for (int n = n0; n < n0 + 64; n++) {
            float v = u.Cs[n][c];
            float e = __expf(v - m);
            ssum += e;
            ws += tmi[n] * e * v;
        }
        colp1[tid] = ssum;
        colp2[tid] = ws;
    }
    __syncthreads();
    if (tid < NN) {
        float ssum = colp1[tid] + colp1[tid + 128];
        float ws   = colp2[tid] + colp2[tid + 128];
        colred[tid] = imj[tid] * (ws / ssum);
    }

    // diagonal W (32/2048 blocks): write pass only, reusing phase-1 stats.
    if (jj == (i >> 1) && tid < NN) {
        int jh = i & 1;
        int n = tid;
        float m   = rowm[jh * 128 + n];
        float inv = 1.f / rowsm[jh * 128 + n];
        const float* Crow = &u.Cs[n][jh * 64];
        float* Wb = W + (size_t)i * LL * NN;
        for (int l = 0; l < LL; l++)
            Wb[(size_t)l * NN + n] = __expf(Crow[l] - m) * inv;  // coalesced over n
    }
    __syncthreads();

    // S[i][j0+jh] = (sum_n rowred + sum_l colred) / N   (waves 0,1)
    if (tid < NN) {
        int jh = tid >> 6, t = tid & 63;
        float p = rowred[jh * 128 + t] + rowred[jh * 128 + 64 + t] + colred[jh * 64 + t];
#pragma unroll
        for (int off = 32; off; off >>= 1) p += __shfl_down(p, off);
        if (t == 0) S[i * BSZ + j0 + jh] = p / (float)NN;
    }
}

// ---------------------------------------------------------------------------
// Kernel 2: text_emb_i2s[b,n,d] = sum_l W[b][l][n] * img[b][l][d]
// Grid: (64 b, 3 d-chunks of 256, 8 n-groups of 16).  W chunk staged in LDS.
// R8: k_loss fused into the tail of block (0,0,0) (S is complete: k_i2s
// launches after k_scores; one launch removed).
// ---------------------------------------------------------------------------
__global__ __launch_bounds__(256) void k_i2s(
    const float* __restrict__ W, const float* __restrict__ img,
    const float* __restrict__ S, float* __restrict__ out)
{
    __shared__ float Ws[LL][16];   // 4 KB
    const int b  = blockIdx.x;
    const int ng = blockIdx.z * 16;
    const int d  = blockIdx.y * 256 + threadIdx.x;
    const float* Wb = W + (size_t)b * LL * NN;

    {   // stage W[l][ng..ng+15]: 1024 floats, 4 per thread
        int t4 = threadIdx.x * 4;
        int l = t4 >> 4, noff = t4 & 15;
        float4 w = *(const float4*)(Wb + (size_t)l * NN + ng + noff);
        Ws[l][noff + 0] = w.x; Ws[l][noff + 1] = w.y;
        Ws[l][noff + 2] = w.z; Ws[l][noff + 3] = w.w;
    }
    __syncthreads();

    const float* ib = img + (size_t)b * LL * DD;
    float* ob = out + 1 + (size_t)b * NN * DD + (size_t)ng * DD;  // slot 0 = loss

    float acc[16];
#pragma unroll
    for (int q = 0; q < 16; q++) acc[q] = 0.f;
    for (int l = 0; l < LL; l++) {
        float g = ib[(size_t)l * DD + d];
#pragma unroll
        for (int q = 0; q < 16; q++)
            acc[q] = fmaf(Ws[l][q], g, acc[q]);   // Ws read is broadcast
    }
#pragma unroll
    for (int q = 0; q < 16; q++)
        ob[(size_t)q * DD + d] = acc[q];

    // fused loss: loss = -sum_i( 2*S[i,i] - lse_row_i(S) - lse_col_i(S) ) / B
    if (blockIdx.x == 0 && blockIdx.y == 0 && blockIdx.z == 0 && threadIdx.x < 64) {
        const int t = threadIdx.x;  // 0..63
        float diag = S[t * BSZ + t];
        float m1 = -INFINITY, m2 = -INFINITY;
        for (int jj = 0; jj < BSZ; jj++) {
            m1 = fmaxf(m1, S[t * BSZ + jj]);
            m2 = fmaxf(m2, S[jj * BSZ + t]);
        }
        float s1 = 0.f, s2 = 0.f;
        for (int jj = 0; jj < BSZ; jj++) {
            s1 += __expf(S[t * BSZ + jj] - m1);
            s2 += __expf(S[jj * BSZ + t] - m2);
        }
        float p = 2.f * diag - (m1 + logf(s1)) - (m2 + logf(s2));
#pragma unroll
        for (int off = 32; off; off >>= 1) p += __shfl_down(p, off);
        if (t == 0) out[0] = -p / (float)BSZ;
    }
}

// ---------------------------------------------------------------------------
extern "C" void kernel_launch(void* const* d_in, const int* in_sizes, int n_in,
                              void* d_out, int out_size, void* d_ws, size_t ws_size,
                              hipStream_t stream)
{
    (void)in_sizes; (void)n_in; (void)out_size; (void)ws_size;
    const float* text = (const float*)d_in[0];   // [64,128,768] fp32
    const float* img  = (const float*)d_in[1];   // [64, 64,768] fp32
    const int*   tm   = (const int*)d_in[2];     // [64,128] int32
    const int*   im   = (const int*)d_in[3];     // [64, 64] int32
    float* out = (float*)d_out;                  // [1 + 64*128*768] fp32

    // workspace layout (bytes); total ~21 MB
    char* ws = (char*)d_ws;
    unsigned short* A = (unsigned short*)(ws);                   // 12.58 MB fp16
    unsigned short* B = (unsigned short*)(ws + 12582912);        //  6.29 MB fp16
    float* S = (float*)(ws + 18874368);                          // 16 KB
    float* W = (float*)(ws + 18890752);                          //  2 MB

    k_prep<<<(TQ + IQ) / 256, 256, 0, stream>>>(
        (const float4*)text, (const float4*)img, (ushort4*)A, (ushort4*)B);

    k_scores<<<BSZ * (BSZ / 2), 256, 0, stream>>>(A, B, tm, im, S, W);

    dim3 g2(BSZ, 3, 8);
    k_i2s<<<g2, 256, 0, stream>>>(W, img, S, out);
}